// Round 1
// baseline (472.041 us; speedup 1.0000x reference)
//
#include <hip/hip_runtime.h>
#include <hip/hip_bf16.h>
#include <stdint.h>

// Int8Linear: per-row symmetric int8 quant (w per-output-channel, x per-token),
// int8 GEMM (exact int32 accum via MFMA i8), fused dequant + bf16 bias epilogue.
// M=8192, K=4096, N=4096 for this problem instance.

using i32x4 = __attribute__((ext_vector_type(4))) int;

#define TILE 128
#define BK 64   // int8 elements of K per MFMA / per LDS stage

// ---------------------------------------------------------------------------
// Per-row quantization: one block per row, 256 threads x 16 floats = K=4096.
// scale = max(absmax/127, 1e-12); q = clip(rint(v/scale), -128, 127).
// rintf = round-half-even, matching jnp.round. True division matches jnp.
// ---------------------------------------------------------------------------
__global__ __launch_bounds__(256) void quant_rows_kernel(
    const float* __restrict__ in, int8_t* __restrict__ qout,
    float* __restrict__ scales, int K)
{
    const int row = blockIdx.x;
    const int tid = threadIdx.x;
    const float* r = in + (size_t)row * K;
    const int base = tid * 16;

    float4 f0 = *(const float4*)(r + base + 0);
    float4 f1 = *(const float4*)(r + base + 4);
    float4 f2 = *(const float4*)(r + base + 8);
    float4 f3 = *(const float4*)(r + base + 12);
    float v[16] = {f0.x,f0.y,f0.z,f0.w, f1.x,f1.y,f1.z,f1.w,
                   f2.x,f2.y,f2.z,f2.w, f3.x,f3.y,f3.z,f3.w};

    float amax = 0.f;
#pragma unroll
    for (int i = 0; i < 16; ++i) amax = fmaxf(amax, fabsf(v[i]));

    // wave64 butterfly reduce
#pragma unroll
    for (int off = 32; off >= 1; off >>= 1)
        amax = fmaxf(amax, __shfl_xor(amax, off));

    __shared__ float red[4];
    const int wave = tid >> 6;
    if ((tid & 63) == 0) red[wave] = amax;
    __syncthreads();
    amax = fmaxf(fmaxf(red[0], red[1]), fmaxf(red[2], red[3]));

    const float scale = fmaxf(amax / 127.0f, 1e-12f);
    if (tid == 0) scales[row] = scale;

    union { signed char c[16]; i32x4 vec; } u;
#pragma unroll
    for (int i = 0; i < 16; ++i) {
        float q = rintf(v[i] / scale);          // exact div + RNE, matches jnp
        q = fminf(fmaxf(q, -128.f), 127.f);
        u.c[i] = (signed char)(int)q;
    }
    *(i32x4*)(qout + (size_t)row * K + base) = u.vec;
}

// ---------------------------------------------------------------------------
// int8 GEMM: C[M][N] = A[M][K] . B[N][K]^T, int32 accum, fused dequant.
// m97 structure: 128x128 tile, BK=64, 4 waves (2x2, 64x64 each),
// global_load_lds width=16, 16x16x64 i8 MFMA, 4x4 tiles per wave.
// ---------------------------------------------------------------------------
__global__ __launch_bounds__(256) void gemm_i8_kernel(
    const int8_t* __restrict__ A,   // [M][K] x_i8
    const int8_t* __restrict__ B,   // [N][K] w_i8
    const float*  __restrict__ xs,  // [M] x scales
    const float*  __restrict__ ws,  // [N] w scales
    const float*  __restrict__ bias,// [N] fp32 bias
    float*        __restrict__ out, // [M][N] fp32
    int M, int N, int K)
{
    __shared__ int8_t sA[TILE * BK];   // [128 rows][64 bytes], lane-contiguous
    __shared__ int8_t sB[TILE * BK];

    const int tid  = threadIdx.x;
    const int wave = tid >> 6;
    const int lane = tid & 63;
    const int quad = lane >> 4;
    const int mrow = lane & 15;

    const int bm = blockIdx.y * TILE;
    const int bn = blockIdx.x * TILE;
    const int wm = (wave >> 1) * 64;
    const int wn = (wave & 1) * 64;

    i32x4 acc[4][4];
    const i32x4 zero = {0, 0, 0, 0};
#pragma unroll
    for (int i = 0; i < 4; ++i)
#pragma unroll
        for (int j = 0; j < 4; ++j) acc[i][j] = zero;

    // staging: thread t loads 16B -> LDS byte offset t*16 (= row(t>>2)*64 + (t&3)*16).
    // 256 threads x 16B = 4 KB = 64 rows; two chunks cover 128 rows.
    const int srow = tid >> 2;
    const int soff = (tid & 3) * 16;

    const int8_t* aptr0 = A + (size_t)(bm + srow) * K + soff;
    const int8_t* aptr1 = A + (size_t)(bm + 64 + srow) * K + soff;
    const int8_t* bptr0 = B + (size_t)(bn + srow) * K + soff;
    const int8_t* bptr1 = B + (size_t)(bn + 64 + srow) * K + soff;

    int8_t* sA0 = sA + tid * 16;
    int8_t* sA1 = sA + 4096 + tid * 16;
    int8_t* sB0 = sB + tid * 16;
    int8_t* sB1 = sB + 4096 + tid * 16;

    for (int k0 = 0; k0 < K; k0 += BK) {
        __syncthreads();   // protect LDS from overwrite while prev iter reads
        __builtin_amdgcn_global_load_lds(
            (const __attribute__((address_space(1))) void*)(aptr0 + k0),
            (__attribute__((address_space(3))) void*)sA0, 16, 0, 0);
        __builtin_amdgcn_global_load_lds(
            (const __attribute__((address_space(1))) void*)(aptr1 + k0),
            (__attribute__((address_space(3))) void*)sA1, 16, 0, 0);
        __builtin_amdgcn_global_load_lds(
            (const __attribute__((address_space(1))) void*)(bptr0 + k0),
            (__attribute__((address_space(3))) void*)sB0, 16, 0, 0);
        __builtin_amdgcn_global_load_lds(
            (const __attribute__((address_space(1))) void*)(bptr1 + k0),
            (__attribute__((address_space(3))) void*)sB1, 16, 0, 0);
        __syncthreads();   // drains vmcnt(0) then barrier

        // A/B fragments: m(or n)=lane&15, k = quad*16 + j (i8 K=64 layout:
        // bf16 16x16x32 mapping with doubled per-lane K)
        i32x4 af[4], bfr[4];
#pragma unroll
        for (int i = 0; i < 4; ++i)
            af[i] = *(const i32x4*)(sA + (wm + i * 16 + mrow) * BK + quad * 16);
#pragma unroll
        for (int j = 0; j < 4; ++j)
            bfr[j] = *(const i32x4*)(sB + (wn + j * 16 + mrow) * BK + quad * 16);

#pragma unroll
        for (int i = 0; i < 4; ++i)
#pragma unroll
            for (int j = 0; j < 4; ++j)
                acc[i][j] = __builtin_amdgcn_mfma_i32_16x16x64_i8(
                    af[i], bfr[j], acc[i][j], 0, 0, 0);
    }

    // Epilogue: out = fp32( bf16( bf16(acc*xs*ws) + bf16(bias) ) )
    // C/D layout: col = lane&15, row = quad*4 + reg (m89-verified, dtype-indep)
#pragma unroll
    for (int j = 0; j < 4; ++j) {
        const int col = bn + wn + j * 16 + mrow;
        const float wsv = ws[col];
        const float bsv = __bfloat162float(__float2bfloat16(bias[col]));
#pragma unroll
        for (int i = 0; i < 4; ++i) {
            const int rowbase = bm + wm + i * 16 + quad * 4;
#pragma unroll
            for (int r = 0; r < 4; ++r) {
                const int row = rowbase + r;
                const float v = (float)acc[i][j][r] * xs[row] * wsv; // (acc*xs)*ws order
                const float vb = __bfloat162float(__float2bfloat16(v));
                const float res = __bfloat162float(__float2bfloat16(vb + bsv));
                out[(size_t)row * N + col] = res;
            }
        }
    }
}

// ---------------------------------------------------------------------------
extern "C" void kernel_launch(void* const* d_in, const int* in_sizes, int n_in,
                              void* d_out, int out_size, void* d_ws, size_t ws_size,
                              hipStream_t stream)
{
    const float* x    = (const float*)d_in[0];   // [B,S,K] fp32
    const float* wfp  = (const float*)d_in[1];   // [N,K] fp32
    const float* bias = (const float*)d_in[2];   // [N] fp32
    float* out = (float*)d_out;                  // [M,N] fp32

    const int N = in_sizes[2];
    const int K = in_sizes[1] / N;
    const int M = in_sizes[0] / K;

    // workspace layout: w_i8[N*K] | x_i8[M*K] | w_scales[N] | x_scales[M]
    int8_t* w_i8 = (int8_t*)d_ws;
    int8_t* x_i8 = w_i8 + (size_t)N * K;
    float* w_scales = (float*)(x_i8 + (size_t)M * K);
    float* x_scales = w_scales + N;

    quant_rows_kernel<<<N, 256, 0, stream>>>(wfp, w_i8, w_scales, K);
    quant_rows_kernel<<<M, 256, 0, stream>>>(x,   x_i8, x_scales, K);

    dim3 grid(N / TILE, M / TILE);
    gemm_i8_kernel<<<grid, 256, 0, stream>>>(x_i8, w_i8, x_scales, w_scales,
                                             bias, out, M, N, K);
}

// Round 2
// 464.452 us; speedup vs baseline: 1.0163x; 1.0163x over previous
//
#include <hip/hip_runtime.h>
#include <hip/hip_bf16.h>
#include <stdint.h>

// Int8Linear: per-row symmetric int8 quant (w per-output-channel, x per-token),
// int8 GEMM (exact int32 accum via MFMA i8), fused dequant + bf16 bias epilogue.
// M=8192, K=4096, N=4096 for this problem instance.
//
// R2 changes vs R1:
//  - quant: lane-contiguous loads (tid*4 + j*1024) instead of 64B-strided
//  - gemm: XOR-ish chunk swizzle on LDS staging source so ds_read_b128
//    fragment reads hit 8 distinct bank-groups per 8-lane phase
//    (R1: 1.68e7 SQ_LDS_BANK_CONFLICT ~= 11% of gemm cycles)

using i32x4 = __attribute__((ext_vector_type(4))) int;

#define TILE 128
#define BK 64   // int8 elements of K per LDS stage

// ---------------------------------------------------------------------------
// Per-row quantization, one block per row, 256 threads, K=4096.
// scale = max(absmax/127, 1e-12); q = clip(rint(v/scale), -128, 127).
// Lane-contiguous: thread t owns elements {t*4 + j*1024 .. +3}, j=0..3.
// ---------------------------------------------------------------------------
__global__ __launch_bounds__(256) void quant_rows_kernel(
    const float* __restrict__ in, int8_t* __restrict__ qout,
    float* __restrict__ scales, int K)
{
    const int row = blockIdx.x;
    const int tid = threadIdx.x;
    const float* r = in + (size_t)row * K;

    float4 v[4];
#pragma unroll
    for (int j = 0; j < 4; ++j)
        v[j] = *(const float4*)(r + j * 1024 + tid * 4);   // coalesced 1KB/wave

    float amax = 0.f;
#pragma unroll
    for (int j = 0; j < 4; ++j) {
        amax = fmaxf(amax, fabsf(v[j].x));
        amax = fmaxf(amax, fabsf(v[j].y));
        amax = fmaxf(amax, fabsf(v[j].z));
        amax = fmaxf(amax, fabsf(v[j].w));
    }

    // wave64 butterfly reduce
#pragma unroll
    for (int off = 32; off >= 1; off >>= 1)
        amax = fmaxf(amax, __shfl_xor(amax, off));

    __shared__ float red[4];
    const int wave = tid >> 6;
    if ((tid & 63) == 0) red[wave] = amax;
    __syncthreads();
    amax = fmaxf(fmaxf(red[0], red[1]), fmaxf(red[2], red[3]));

    const float scale = fmaxf(amax / 127.0f, 1e-12f);
    if (tid == 0) scales[row] = scale;

#pragma unroll
    for (int j = 0; j < 4; ++j) {
        float q0 = fminf(fmaxf(rintf(v[j].x / scale), -128.f), 127.f);
        float q1 = fminf(fmaxf(rintf(v[j].y / scale), -128.f), 127.f);
        float q2 = fminf(fmaxf(rintf(v[j].z / scale), -128.f), 127.f);
        float q3 = fminf(fmaxf(rintf(v[j].w / scale), -128.f), 127.f);
        union { signed char c[4]; int i; } u;
        u.c[0] = (signed char)(int)q0;
        u.c[1] = (signed char)(int)q1;
        u.c[2] = (signed char)(int)q2;
        u.c[3] = (signed char)(int)q3;
        *(int*)(qout + (size_t)row * K + j * 1024 + tid * 4) = u.i;  // 256B/wave
    }
}

// ---------------------------------------------------------------------------
// int8 GEMM: C[M][N] = A[M][K] . B[N][K]^T, int32 accum, fused dequant.
// 128x128 tile, BK=64, 4 waves (2x2, 64x64 each), global_load_lds width=16,
// 16x16x64 i8 MFMA, 4x4 tiles per wave.
//
// LDS bank swizzle: physical chunk c (16B) of row r holds logical k-chunk
// (c - (r>>1)) & 3. Staged by permuting the *global source* chunk per thread
// (LDS dst must stay base + lane*16 for global_load_lds). Fragment reads
// fetch physical chunk (quad + (mrow>>1)) & 3 -> logical chunk quad.
// Bank of lane addr = (16*row + 4*chunk) % 32: any 8 consecutive lanes
// hit 8 distinct 4-bank groups -> conflict-free.
// ---------------------------------------------------------------------------
__global__ __launch_bounds__(256) void gemm_i8_kernel(
    const int8_t* __restrict__ A,   // [M][K] x_i8
    const int8_t* __restrict__ B,   // [N][K] w_i8
    const float*  __restrict__ xs,  // [M] x scales
    const float*  __restrict__ ws,  // [N] w scales
    const float*  __restrict__ bias,// [N] fp32 bias
    float*        __restrict__ out, // [M][N] fp32
    int M, int N, int K)
{
    __shared__ int8_t sA[TILE * BK];   // [128 rows][64 bytes]
    __shared__ int8_t sB[TILE * BK];

    const int tid  = threadIdx.x;
    const int wave = tid >> 6;
    const int lane = tid & 63;
    const int quad = lane >> 4;
    const int mrow = lane & 15;

    const int bm = blockIdx.y * TILE;
    const int bn = blockIdx.x * TILE;
    const int wm = (wave >> 1) * 64;
    const int wn = (wave & 1) * 64;

    i32x4 acc[4][4];
    const i32x4 zero = {0, 0, 0, 0};
#pragma unroll
    for (int i = 0; i < 4; ++i)
#pragma unroll
        for (int j = 0; j < 4; ++j) acc[i][j] = zero;

    // staging: thread t -> LDS offset t*16 (physical row t>>2, chunk t&3).
    // source chunk g = ((t&3) - (t>>3)) & 3 implements the swizzle.
    const int srow = tid >> 2;
    const int g    = ((tid & 3) - ((tid >> 3) & 3)) & 3;
    const int soff = g * 16;

    const int8_t* aptr0 = A + (size_t)(bm + srow) * K + soff;
    const int8_t* aptr1 = A + (size_t)(bm + 64 + srow) * K + soff;
    const int8_t* bptr0 = B + (size_t)(bn + srow) * K + soff;
    const int8_t* bptr1 = B + (size_t)(bn + 64 + srow) * K + soff;

    int8_t* sA0 = sA + tid * 16;
    int8_t* sA1 = sA + 4096 + tid * 16;
    int8_t* sB0 = sB + tid * 16;
    int8_t* sB1 = sB + 4096 + tid * 16;

    // fragment-read physical chunk (loop-invariant, lane-only)
    const int rchunk = ((quad + (mrow >> 1)) & 3) * 16;

    for (int k0 = 0; k0 < K; k0 += BK) {
        __syncthreads();   // protect LDS from overwrite while prev iter reads
        __builtin_amdgcn_global_load_lds(
            (const __attribute__((address_space(1))) void*)(aptr0 + k0),
            (__attribute__((address_space(3))) void*)sA0, 16, 0, 0);
        __builtin_amdgcn_global_load_lds(
            (const __attribute__((address_space(1))) void*)(aptr1 + k0),
            (__attribute__((address_space(3))) void*)sA1, 16, 0, 0);
        __builtin_amdgcn_global_load_lds(
            (const __attribute__((address_space(1))) void*)(bptr0 + k0),
            (__attribute__((address_space(3))) void*)sB0, 16, 0, 0);
        __builtin_amdgcn_global_load_lds(
            (const __attribute__((address_space(1))) void*)(bptr1 + k0),
            (__attribute__((address_space(3))) void*)sB1, 16, 0, 0);
        __syncthreads();   // drains vmcnt(0) then barrier

        // A/B fragments: m(or n)=lane&15, logical k = quad*16 + j
        i32x4 af[4], bfr[4];
#pragma unroll
        for (int i = 0; i < 4; ++i)
            af[i] = *(const i32x4*)(sA + (wm + i * 16 + mrow) * BK + rchunk);
#pragma unroll
        for (int j = 0; j < 4; ++j)
            bfr[j] = *(const i32x4*)(sB + (wn + j * 16 + mrow) * BK + rchunk);

#pragma unroll
        for (int i = 0; i < 4; ++i)
#pragma unroll
            for (int j = 0; j < 4; ++j)
                acc[i][j] = __builtin_amdgcn_mfma_i32_16x16x64_i8(
                    af[i], bfr[j], acc[i][j], 0, 0, 0);
    }

    // Epilogue: out = fp32( bf16( bf16(acc*xs*ws) + bf16(bias) ) )
    // C/D layout: col = lane&15, row = quad*4 + reg (m89-verified, dtype-indep)
#pragma unroll
    for (int j = 0; j < 4; ++j) {
        const int col = bn + wn + j * 16 + mrow;
        const float wsv = ws[col];
        const float bsv = __bfloat162float(__float2bfloat16(bias[col]));
#pragma unroll
        for (int i = 0; i < 4; ++i) {
            const int rowbase = bm + wm + i * 16 + quad * 4;
#pragma unroll
            for (int r = 0; r < 4; ++r) {
                const int row = rowbase + r;
                const float v = (float)acc[i][j][r] * xs[row] * wsv;
                const float vb = __bfloat162float(__float2bfloat16(v));
                const float res = __bfloat162float(__float2bfloat16(vb + bsv));
                out[(size_t)row * N + col] = res;
            }
        }
    }
}

// ---------------------------------------------------------------------------
extern "C" void kernel_launch(void* const* d_in, const int* in_sizes, int n_in,
                              void* d_out, int out_size, void* d_ws, size_t ws_size,
                              hipStream_t stream)
{
    const float* x    = (const float*)d_in[0];   // [B,S,K] fp32
    const float* wfp  = (const float*)d_in[1];   // [N,K] fp32
    const float* bias = (const float*)d_in[2];   // [N] fp32
    float* out = (float*)d_out;                  // [M,N] fp32

    const int N = in_sizes[2];
    const int K = in_sizes[1] / N;
    const int M = in_sizes[0] / K;

    // workspace layout: w_i8[N*K] | x_i8[M*K] | w_scales[N] | x_scales[M]
    int8_t* w_i8 = (int8_t*)d_ws;
    int8_t* x_i8 = w_i8 + (size_t)N * K;
    float* w_scales = (float*)(x_i8 + (size_t)M * K);
    float* x_scales = w_scales + N;

    quant_rows_kernel<<<N, 256, 0, stream>>>(wfp, w_i8, w_scales, K);
    quant_rows_kernel<<<M, 256, 0, stream>>>(x,   x_i8, x_scales, K);

    dim3 grid(N / TILE, M / TILE);
    gemm_i8_kernel<<<grid, 256, 0, stream>>>(x_i8, w_i8, x_scales, w_scales,
                                             bias, out, M, N, K);
}

// Round 3
// 441.875 us; speedup vs baseline: 1.0683x; 1.0511x over previous
//
#include <hip/hip_runtime.h>
#include <hip/hip_bf16.h>
#include <stdint.h>

// Int8Linear: per-row symmetric int8 quant (w per-output-channel, x per-token),
// int8 GEMM (exact int32 accum via MFMA i8), fused dequant + bf16 bias epilogue.
// M=8192, K=4096, N=4096 for this problem instance.
//
// R3 changes vs R2:
//  - gemm: 16x16x64 -> 32x32x32 i8 MFMA (half the MFMA instrs for same ops,
//    4404 vs 3944 TOPS ceiling). Wave tile stays 64x64 (2x2 MFMAs of 32x32).
//  - both quant launches fused into one dispatch (grid N+M).
// R2 established: LDS chunk swizzle -> SQ_LDS_BANK_CONFLICT = 0. Kept.

using i32x4  = __attribute__((ext_vector_type(4))) int;
using i32x16 = __attribute__((ext_vector_type(16))) int;

#define TILE 128
#define BK 64   // int8 elements of K per LDS stage

// ---------------------------------------------------------------------------
// Fused per-row quantization for both W [N,K] and X [M,K]; block b < nw does
// weight row b, else x row b-nw. 256 threads, K=4096.
// scale = max(absmax/127, 1e-12); q = clip(rint(v/scale), -128, 127).
// ---------------------------------------------------------------------------
__global__ __launch_bounds__(256) void quant_rows_fused(
    const float* __restrict__ w_in, const float* __restrict__ x_in,
    int8_t* __restrict__ w_q, int8_t* __restrict__ x_q,
    float* __restrict__ w_s, float* __restrict__ x_s,
    int nw, int K)
{
    const int b   = blockIdx.x;
    const bool is_w = (b < nw);
    const int row = is_w ? b : (b - nw);
    const float* r = (is_w ? w_in : x_in) + (size_t)row * K;
    int8_t* qout   = (is_w ? w_q : x_q) + (size_t)row * K;
    float* scales  = is_w ? w_s : x_s;

    const int tid = threadIdx.x;

    float4 v[4];
#pragma unroll
    for (int j = 0; j < 4; ++j)
        v[j] = *(const float4*)(r + j * 1024 + tid * 4);   // coalesced

    float amax = 0.f;
#pragma unroll
    for (int j = 0; j < 4; ++j) {
        amax = fmaxf(amax, fabsf(v[j].x));
        amax = fmaxf(amax, fabsf(v[j].y));
        amax = fmaxf(amax, fabsf(v[j].z));
        amax = fmaxf(amax, fabsf(v[j].w));
    }

#pragma unroll
    for (int off = 32; off >= 1; off >>= 1)
        amax = fmaxf(amax, __shfl_xor(amax, off));

    __shared__ float red[4];
    const int wave = tid >> 6;
    if ((tid & 63) == 0) red[wave] = amax;
    __syncthreads();
    amax = fmaxf(fmaxf(red[0], red[1]), fmaxf(red[2], red[3]));

    const float scale = fmaxf(amax / 127.0f, 1e-12f);
    if (tid == 0) scales[row] = scale;

#pragma unroll
    for (int j = 0; j < 4; ++j) {
        float q0 = fminf(fmaxf(rintf(v[j].x / scale), -128.f), 127.f);
        float q1 = fminf(fmaxf(rintf(v[j].y / scale), -128.f), 127.f);
        float q2 = fminf(fmaxf(rintf(v[j].z / scale), -128.f), 127.f);
        float q3 = fminf(fmaxf(rintf(v[j].w / scale), -128.f), 127.f);
        union { signed char c[4]; int i; } u;
        u.c[0] = (signed char)(int)q0;
        u.c[1] = (signed char)(int)q1;
        u.c[2] = (signed char)(int)q2;
        u.c[3] = (signed char)(int)q3;
        *(int*)(qout + j * 1024 + tid * 4) = u.i;
    }
}

// ---------------------------------------------------------------------------
// int8 GEMM: C[M][N] = A[M][K] . B[N][K]^T, int32 accum, fused dequant.
// 128x128 tile, BK=64, 4 waves (2x2, 64x64 each), global_load_lds width=16,
// 32x32x32 i8 MFMA, 2x2 MFMA tiles per wave.
//
// LDS swizzle (R2, verified conflict-free): physical 16B chunk c of row r
// holds logical k-chunk (c - (r>>1)) & 3; staged by permuting the global
// source chunk per thread. Readers: phys = (logical + (r>>1)) & 3.
//
// 32x32x32 i8 layouts:
//   A: m = lane&31, k = (lane>>5)*16 + j   (16 i8 per lane = i32x4)
//   B: n = lane&31, k = (lane>>5)*16 + j
//   C/D: col = lane&31, row = (reg&3) + 8*(reg>>2) + 4*(lane>>5)  [m74/m101]
// ---------------------------------------------------------------------------
__global__ __launch_bounds__(256) void gemm_i8_kernel(
    const int8_t* __restrict__ A,   // [M][K] x_i8
    const int8_t* __restrict__ B,   // [N][K] w_i8
    const float*  __restrict__ xs,  // [M] x scales
    const float*  __restrict__ ws,  // [N] w scales
    const float*  __restrict__ bias,// [N] fp32 bias
    float*        __restrict__ out, // [M][N] fp32
    int M, int N, int K)
{
    __shared__ int8_t sA[TILE * BK];   // [128 rows][64 bytes]
    __shared__ int8_t sB[TILE * BK];

    const int tid   = threadIdx.x;
    const int wave  = tid >> 6;
    const int lane  = tid & 63;
    const int l31   = lane & 31;
    const int lhalf = lane >> 5;       // 0/1

    const int bm = blockIdx.y * TILE;
    const int bn = blockIdx.x * TILE;
    const int wm = (wave >> 1) * 64;
    const int wn = (wave & 1) * 64;

    i32x16 acc[2][2];
#pragma unroll
    for (int i = 0; i < 2; ++i)
#pragma unroll
        for (int j = 0; j < 2; ++j)
#pragma unroll
            for (int r = 0; r < 16; ++r) acc[i][j][r] = 0;

    // staging: thread t -> LDS offset t*16 (physical row t>>2, chunk t&3).
    // source chunk g = ((t&3) - (t>>3)) & 3 implements the swizzle.
    const int srow = tid >> 2;
    const int g    = ((tid & 3) - ((tid >> 3) & 3)) & 3;
    const int soff = g * 16;

    const int8_t* aptr0 = A + (size_t)(bm + srow) * K + soff;
    const int8_t* aptr1 = A + (size_t)(bm + 64 + srow) * K + soff;
    const int8_t* bptr0 = B + (size_t)(bn + srow) * K + soff;
    const int8_t* bptr1 = B + (size_t)(bn + 64 + srow) * K + soff;

    int8_t* sA0 = sA + tid * 16;
    int8_t* sA1 = sA + 4096 + tid * 16;
    int8_t* sB0 = sB + tid * 16;
    int8_t* sB1 = sB + 4096 + tid * 16;

    // fragment-read physical chunks: logical chunk = lhalf + khalf*2,
    // row parity term = (l31>>1) (wm, it*32 are 0 mod 8 after >>1, drop out)
    const int pc0 = ((lhalf + 0 + (l31 >> 1)) & 3) * 16;   // khalf=0
    const int pc1 = ((lhalf + 2 + (l31 >> 1)) & 3) * 16;   // khalf=1

    for (int k0 = 0; k0 < K; k0 += BK) {
        __syncthreads();
        __builtin_amdgcn_global_load_lds(
            (const __attribute__((address_space(1))) void*)(aptr0 + k0),
            (__attribute__((address_space(3))) void*)sA0, 16, 0, 0);
        __builtin_amdgcn_global_load_lds(
            (const __attribute__((address_space(1))) void*)(aptr1 + k0),
            (__attribute__((address_space(3))) void*)sA1, 16, 0, 0);
        __builtin_amdgcn_global_load_lds(
            (const __attribute__((address_space(1))) void*)(bptr0 + k0),
            (__attribute__((address_space(3))) void*)sB0, 16, 0, 0);
        __builtin_amdgcn_global_load_lds(
            (const __attribute__((address_space(1))) void*)(bptr1 + k0),
            (__attribute__((address_space(3))) void*)sB1, 16, 0, 0);
        __syncthreads();

        i32x4 af[2][2], bf[2][2];   // [it or jt][khalf]
#pragma unroll
        for (int it = 0; it < 2; ++it) {
            const int arow = (wm + it * 32 + l31) * BK;
            af[it][0] = *(const i32x4*)(sA + arow + pc0);
            af[it][1] = *(const i32x4*)(sA + arow + pc1);
        }
#pragma unroll
        for (int jt = 0; jt < 2; ++jt) {
            const int brow = (wn + jt * 32 + l31) * BK;
            bf[jt][0] = *(const i32x4*)(sB + brow + pc0);
            bf[jt][1] = *(const i32x4*)(sB + brow + pc1);
        }

#pragma unroll
        for (int kh = 0; kh < 2; ++kh)
#pragma unroll
            for (int it = 0; it < 2; ++it)
#pragma unroll
                for (int jt = 0; jt < 2; ++jt)
                    acc[it][jt] = __builtin_amdgcn_mfma_i32_32x32x32_i8(
                        af[it][kh], bf[jt][kh], acc[it][jt], 0, 0, 0);
    }

    // Epilogue: out = fp32( bf16( bf16(acc*xs*ws) + bf16(bias) ) )
    // C/D: col = lane&31, row = (reg&3) + 8*(reg>>2) + 4*(lane>>5)
#pragma unroll
    for (int jt = 0; jt < 2; ++jt) {
        const int col = bn + wn + jt * 32 + l31;
        const float wsv = ws[col];
        const float bsv = __bfloat162float(__float2bfloat16(bias[col]));
#pragma unroll
        for (int it = 0; it < 2; ++it) {
            const int rowbase = bm + wm + it * 32 + 4 * lhalf;
#pragma unroll
            for (int r = 0; r < 16; ++r) {
                const int row = rowbase + (r & 3) + 8 * (r >> 2);
                const float v = (float)acc[it][jt][r] * xs[row] * wsv;
                const float vb = __bfloat162float(__float2bfloat16(v));
                const float res = __bfloat162float(__float2bfloat16(vb + bsv));
                out[(size_t)row * N + col] = res;
            }
        }
    }
}

// ---------------------------------------------------------------------------
extern "C" void kernel_launch(void* const* d_in, const int* in_sizes, int n_in,
                              void* d_out, int out_size, void* d_ws, size_t ws_size,
                              hipStream_t stream)
{
    const float* x    = (const float*)d_in[0];   // [B,S,K] fp32
    const float* wfp  = (const float*)d_in[1];   // [N,K] fp32
    const float* bias = (const float*)d_in[2];   // [N] fp32
    float* out = (float*)d_out;                  // [M,N] fp32

    const int N = in_sizes[2];
    const int K = in_sizes[1] / N;
    const int M = in_sizes[0] / K;

    // workspace layout: w_i8[N*K] | x_i8[M*K] | w_scales[N] | x_scales[M]
    int8_t* w_i8 = (int8_t*)d_ws;
    int8_t* x_i8 = w_i8 + (size_t)N * K;
    float* w_scales = (float*)(x_i8 + (size_t)M * K);
    float* x_scales = w_scales + N;

    quant_rows_fused<<<N + M, 256, 0, stream>>>(wfp, x, w_i8, x_i8,
                                                w_scales, x_scales, N, K);

    dim3 grid(N / TILE, M / TILE);
    gemm_i8_kernel<<<grid, 256, 0, stream>>>(x_i8, w_i8, x_scales, w_scales,
                                             bias, out, M, N, K);
}